// Round 5
// baseline (446.299 us; speedup 1.0000x reference)
//
#include <hip/hip_runtime.h>
#include <cstdint>
#include <cstddef>

typedef __bf16 bf16;
typedef __bf16 bf16x8 __attribute__((ext_vector_type(8)));
typedef __bf16 bf16v4 __attribute__((ext_vector_type(4)));
typedef float  f32x4  __attribute__((ext_vector_type(4)));

// Problem constants: B=128, N=49, G=4096, H=1024, A=1024
#define PB   128
#define PN   49
#define PG   4096
#define PH   1024
#define PA   1024
#define PM1  (PB * PN)   // 6272

// ---------------------------------------------------------------------------
// dtype detect: flag=1 -> bf16 inputs, 0 -> fp32.
// ---------------------------------------------------------------------------
__global__ __launch_bounds__(256) void detect_kernel(
    const unsigned short* __restrict__ raw, int* __restrict__ flag)
{
    __shared__ int cnt;
    if (threadIdx.x == 0) cnt = 0;
    __syncthreads();
    unsigned short u = raw[threadIdx.x];
    float x = __uint_as_float(((unsigned int)u) << 16);
    float a = fabsf(x);
    atomicAdd(&cnt, (a >= 1e-7f && a <= 128.f) ? 1 : 0);
    __syncthreads();
    if (threadIdx.x == 0) flag[0] = (cnt >= 200) ? 1 : 0;
}

__device__ __forceinline__ float ldin(const void* p, size_t i, bool in32) {
    return in32 ? ((const float*)p)[i] : (float)((const bf16*)p)[i];
}

// load 8 consecutive elems of x (fp32 or bf16) as float
__device__ __forceinline__ void ldx8(const void* x, size_t k0, bool in32, float* xv) {
    if (in32) {
        f32x4 lo = *(const f32x4*)((const float*)x + k0);
        f32x4 hi = *(const f32x4*)((const float*)x + k0 + 4);
#pragma unroll
        for (int j = 0; j < 4; ++j) { xv[j] = lo[j]; xv[4 + j] = hi[j]; }
    } else {
        bf16x8 v = *(const bf16x8*)((const bf16*)x + k0);
#pragma unroll
        for (int j = 0; j < 8; ++j) xv[j] = (float)v[j];
    }
}

// ---------------------------------------------------------------------------
// Fused 3-region cvt (raw -> bf16), unit = 2048 elems (256 thr x 8).
// Also zeroes the sc accumulator (block 0) for the fused-scores epilogue.
// Dispatch-count reduction: 3 cvt kernels + 1 zero pass -> 1 dispatch.
// ---------------------------------------------------------------------------
__global__ __launch_bounds__(256) void cvt3_kernel(
    const void* __restrict__ in0, size_t u0, bf16* __restrict__ o0,
    const void* __restrict__ in1, size_t u1, bf16* __restrict__ o1,
    const void* __restrict__ in2, size_t u2, bf16* __restrict__ o2,
    const int* __restrict__ flag, float* __restrict__ sc_zero, int sczn)
{
    if (blockIdx.x == 0) {
        for (int i = threadIdx.x; i < sczn; i += 256) sc_zero[i] = 0.f;
    }
    const bool in32 = (flag[0] == 0);
    const size_t total = u0 + u1 + u2;
    for (size_t u = blockIdx.x; u < total; u += gridDim.x) {
        const void* in; bf16* out; size_t rel;
        if (u < u0)            { in = in0; out = o0; rel = u; }
        else if (u < u0 + u1)  { in = in1; out = o1; rel = u - u0; }
        else                   { in = in2; out = o2; rel = u - u0 - u1; }
        size_t i = rel * 2048 + (size_t)threadIdx.x * 8;
        bf16x8 o;
        if (in32) {
            f32x4 lo = *(const f32x4*)((const float*)in + i);
            f32x4 hi = *(const f32x4*)((const float*)in + i + 4);
#pragma unroll
            for (int j = 0; j < 4; ++j) { o[j] = (bf16)lo[j]; o[4 + j] = (bf16)hi[j]; }
        } else {
            o = *(const bf16x8*)((const bf16*)in + i);
        }
        *(bf16x8*)(out + i) = o;
    }
}

// ---------------------------------------------------------------------------
// GEMM: C[M,N] = A[M,K] @ Bt^T.  128x128 tile, BK=64, 4 waves,
// mfma 16x16x32 bf16.  Both operands bf16, staged via global_load_lds(16B)
// async DMA with (chunk+row)&7 source rotation (0 bank conflicts, verified).
// Bijective XCD-aware block swizzle (m204).  Split-K via bz plane.
// ---------------------------------------------------------------------------
template <int BF16OUT>
__global__ __launch_bounds__(256, 2) void gemm_kernel(
    const bf16* __restrict__ A, const bf16* __restrict__ Bt0,
    float* __restrict__ Cf, bf16* __restrict__ Cb,
    int M, int N, int K, int kTilesPerSplit)
{
    __shared__ __align__(16) bf16 lds[2 * 128 * 64];
    bf16* As  = lds;
    bf16* Bs0 = lds + 128 * 64;

    const int gx = gridDim.x, gy = gridDim.y;
    const int nwg = gx * gy * (int)gridDim.z;
    int flat = blockIdx.x + gx * (blockIdx.y + gy * blockIdx.z);
    {
        const int q8 = nwg >> 3, r8 = nwg & 7;
        const int xcd = flat & 7, sub = flat >> 3;
        flat = (xcd < r8 ? xcd * (q8 + 1) : r8 * (q8 + 1) + (xcd - r8) * q8) + sub;
    }
    const int bx  = flat % gx;
    const int byz = flat / gx;
    const int by  = byz % gy;
    const int bz  = byz / gy;

    const int tid  = threadIdx.x;
    const int m0   = by * 128;
    const int n0   = bx * 128;
    const int kt0  = bz * kTilesPerSplit;

    const int wave = tid >> 6;
    const int lane = tid & 63;
    const int wm   = (wave >> 1) * 64;
    const int wn   = (wave & 1) * 64;
    const int lm   = lane & 15;
    const int q    = lane >> 4;

    f32x4 acc[4][4];
#pragma unroll
    for (int i = 0; i < 4; ++i)
#pragma unroll
        for (int j = 0; j < 4; ++j) acc[i][j] = (f32x4)0.0f;

    for (int kt = 0; kt < kTilesPerSplit; ++kt) {
        const int k0 = (kt0 + kt) * 64;
#pragma unroll
        for (int it = 0; it < 4; ++it) {
            int p   = it * 256 + tid;
            int row = p >> 3;
            int lc  = ((p & 7) - row) & 7;
            size_t offB = (size_t)(n0 + row) * K + k0 + lc * 8;
            __builtin_amdgcn_global_load_lds((void*)(Bt0 + offB), (void*)(Bs0 + p * 8), 16, 0, 0);
            size_t offA = (size_t)(m0 + row) * K + k0 + lc * 8;
            __builtin_amdgcn_global_load_lds((void*)(A + offA), (void*)(As + p * 8), 16, 0, 0);
        }
        __syncthreads();

#pragma unroll
        for (int s = 0; s < 2; ++s) {
            bf16x8 af[4], bf0[4];
            const int c = s * 4 + q;
#pragma unroll
            for (int mi = 0; mi < 4; ++mi) {
                int row  = wm + mi * 16 + lm;
                int slot = row * 8 + ((c + row) & 7);
                af[mi] = *(const bf16x8*)(As + slot * 8);
            }
#pragma unroll
            for (int ni = 0; ni < 4; ++ni) {
                int row  = wn + ni * 16 + lm;
                int slot = row * 8 + ((c + row) & 7);
                bf0[ni] = *(const bf16x8*)(Bs0 + slot * 8);
            }
#pragma unroll
            for (int mi = 0; mi < 4; ++mi)
#pragma unroll
                for (int ni = 0; ni < 4; ++ni)
                    acc[mi][ni] = __builtin_amdgcn_mfma_f32_16x16x32_bf16(
                        af[mi], bf0[ni], acc[mi][ni], 0, 0, 0);
        }
        __syncthreads();
    }

#pragma unroll
    for (int mi = 0; mi < 4; ++mi)
#pragma unroll
        for (int ni = 0; ni < 4; ++ni)
#pragma unroll
            for (int r = 0; r < 4; ++r) {
                int row = m0 + wm + mi * 16 + q * 4 + r;
                int col = n0 + wn + ni * 16 + lm;
                if (BF16OUT)
                    Cb[(size_t)bz * M * N + (size_t)row * N + col] = (bf16)acc[mi][ni][r];
                else
                    Cf[(size_t)bz * M * N + (size_t)row * N + col] = acc[mi][ni][r];
            }
}

// ---------------------------------------------------------------------------
// Fused t2-GEMM + scores: sc[m] += sum_col v[col]*tanh(t2[m,col] + sproj +
// tbias + cov*Wc).  A = g_star [PM1,PH], Bt = WhT [PA,PH], no split-K (tanh
// needs the full K sum).  Same staging/MFMA core as gemm_kernel; epilogue
// does the tanh + 16-lane shuffle row-reduce + one atomicAdd per row-half.
// Replaces the t2P plane write (25.7 MiB) + scores kernel (126 MB read).
// grid (PA/128, PM1/128) = (8,49); sc must be pre-zeroed (done in cvt3).
// ---------------------------------------------------------------------------
__global__ __launch_bounds__(256, 2) void gemm_scores_kernel(
    const bf16* __restrict__ A, const bf16* __restrict__ Bt0,
    const float* __restrict__ sprojP, const float* __restrict__ tbias,
    const void* __restrict__ cov, const void* __restrict__ Wc,
    const void* __restrict__ v, const int* __restrict__ flag,
    float* __restrict__ sc)
{
    constexpr int K = PH;
    __shared__ __align__(16) bf16 lds[2 * 128 * 64];
    bf16* As  = lds;
    bf16* Bs0 = lds + 128 * 64;

    const int gx = gridDim.x, gy = gridDim.y;
    const int nwg = gx * gy;
    int flat = blockIdx.x + gx * blockIdx.y;
    {
        const int q8 = nwg >> 3, r8 = nwg & 7;
        const int xcd = flat & 7, sub = flat >> 3;
        flat = (xcd < r8 ? xcd * (q8 + 1) : r8 * (q8 + 1) + (xcd - r8) * q8) + sub;
    }
    const int bx = flat % gx;
    const int by = flat / gx;

    const int tid  = threadIdx.x;
    const int m0   = by * 128;
    const int n0   = bx * 128;

    const int wave = tid >> 6;
    const int lane = tid & 63;
    const int wm   = (wave >> 1) * 64;
    const int wn   = (wave & 1) * 64;
    const int lm   = lane & 15;
    const int q    = lane >> 4;

    f32x4 acc[4][4];
#pragma unroll
    for (int i = 0; i < 4; ++i)
#pragma unroll
        for (int j = 0; j < 4; ++j) acc[i][j] = (f32x4)0.0f;

    for (int kt = 0; kt < K / 64; ++kt) {
        const int k0 = kt * 64;
#pragma unroll
        for (int it = 0; it < 4; ++it) {
            int p   = it * 256 + tid;
            int row = p >> 3;
            int lc  = ((p & 7) - row) & 7;
            size_t offB = (size_t)(n0 + row) * K + k0 + lc * 8;
            __builtin_amdgcn_global_load_lds((void*)(Bt0 + offB), (void*)(Bs0 + p * 8), 16, 0, 0);
            size_t offA = (size_t)(m0 + row) * K + k0 + lc * 8;
            __builtin_amdgcn_global_load_lds((void*)(A + offA), (void*)(As + p * 8), 16, 0, 0);
        }
        __syncthreads();

#pragma unroll
        for (int s = 0; s < 2; ++s) {
            bf16x8 af[4], bf0[4];
            const int c = s * 4 + q;
#pragma unroll
            for (int mi = 0; mi < 4; ++mi) {
                int row  = wm + mi * 16 + lm;
                int slot = row * 8 + ((c + row) & 7);
                af[mi] = *(const bf16x8*)(As + slot * 8);
            }
#pragma unroll
            for (int ni = 0; ni < 4; ++ni) {
                int row  = wn + ni * 16 + lm;
                int slot = row * 8 + ((c + row) & 7);
                bf0[ni] = *(const bf16x8*)(Bs0 + slot * 8);
            }
#pragma unroll
            for (int mi = 0; mi < 4; ++mi)
#pragma unroll
                for (int ni = 0; ni < 4; ++ni)
                    acc[mi][ni] = __builtin_amdgcn_mfma_f32_16x16x32_bf16(
                        af[mi], bf0[ni], acc[mi][ni], 0, 0, 0);
        }
        __syncthreads();
    }

    // ---- fused scores epilogue ----
    const bool in32 = (flag[0] == 0);
    float tb[4], wc4[4], vv[4];
#pragma unroll
    for (int ni = 0; ni < 4; ++ni) {
        int col = n0 + wn + ni * 16 + lm;
        tb[ni]  = tbias[col];
        wc4[ni] = ldin(Wc, col, in32);
        vv[ni]  = ldin(v, col, in32);
    }
#pragma unroll
    for (int mi = 0; mi < 4; ++mi)
#pragma unroll
        for (int r = 0; r < 4; ++r) {
            int grow = m0 + wm + mi * 16 + q * 4 + r;
            int b    = grow / PN;
            float cv = ldin(cov, grow, in32);
            const float* sp0 = sprojP + (size_t)b * PA;
            float rowsum = 0.f;
#pragma unroll
            for (int ni = 0; ni < 4; ++ni) {
                int col = n0 + wn + ni * 16 + lm;
                float sp = sp0[col] + sp0[PB * PA + col]
                         + sp0[2 * PB * PA + col] + sp0[3 * PB * PA + col];
                float val = acc[mi][ni][r] + sp + tb[ni] + cv * wc4[ni];
                rowsum += vv[ni] * tanhf(val);
            }
#pragma unroll
            for (int off = 1; off < 16; off <<= 1)
                rowsum += __shfl_xor(rowsum, off);
            if (lm == 0) atomicAdd(&sc[grow], rowsum);
        }
}

// ---------------------------------------------------------------------------
// Batched transpose of the 3 weight inputs (raw dtype -> bf16 [C,R]).
// blocks 0..1023: Wgs [PG,PH]; 1024..1279: Wh [PH,PA]; 1280..1535: Ws.
// ---------------------------------------------------------------------------
__global__ __launch_bounds__(256) void transpose3_kernel(
    const void* __restrict__ inA, bf16* __restrict__ outA,
    const void* __restrict__ inB, bf16* __restrict__ outB,
    const void* __restrict__ inC, bf16* __restrict__ outC,
    const int* __restrict__ flag)
{
    __shared__ bf16 tile[64][65];
    const bool in32 = (flag[0] == 0);
    const int bid = blockIdx.x;
    const void* in; bf16* out; int R, C, bx, by;
    if (bid < 1024)      { in = inA; out = outA; R = PG; C = PH; bx = bid & 15; by = bid >> 4; }
    else if (bid < 1280) { int t = bid - 1024; in = inB; out = outB; R = PH; C = PA; bx = t & 15; by = t >> 4; }
    else                 { int t = bid - 1280; in = inC; out = outC; R = PH; C = PA; bx = t & 15; by = t >> 4; }
    const int r0 = by * 64, c0 = bx * 64;
    const int tx = threadIdx.x & 15, ty = threadIdx.x >> 4;
#pragma unroll
    for (int it = 0; it < 4; ++it) {
        int r = it * 16 + ty;
        size_t base = (size_t)(r0 + r) * C + c0 + tx * 4;
        if (in32) {
            f32x4 vv = *(const f32x4*)((const float*)in + base);
#pragma unroll
            for (int i = 0; i < 4; ++i) tile[r][tx * 4 + i] = (bf16)vv[i];
        } else {
            bf16v4 vv = *(const bf16v4*)((const bf16*)in + base);
#pragma unroll
            for (int i = 0; i < 4; ++i) tile[r][tx * 4 + i] = vv[i];
        }
    }
    __syncthreads();
#pragma unroll
    for (int it = 0; it < 4; ++it) {
        int c = it * 16 + ty;
        bf16v4 vv;
#pragma unroll
        for (int i = 0; i < 4; ++i) vv[i] = tile[tx * 4 + i][c];
        *(bf16v4*)(out + (size_t)(c0 + c) * R + r0 + tx * 4) = vv;
    }
}

// elementwise reduce of PLANES bf16 planes -> single bf16, 8 elems/thread
template <int PLANES>
__global__ __launch_bounds__(256) void reduce_kernel(
    const bf16* __restrict__ in, bf16* __restrict__ out, size_t n)
{
    size_t i = ((size_t)blockIdx.x * 256 + threadIdx.x) * 8;
    float s[8] = {0,0,0,0,0,0,0,0};
#pragma unroll
    for (int p = 0; p < PLANES; ++p) {
        bf16x8 v = *(const bf16x8*)(in + (size_t)p * n + i);
#pragma unroll
        for (int j = 0; j < 8; ++j) s[j] += (float)v[j];
    }
    bf16x8 o;
#pragma unroll
    for (int j = 0; j < 8; ++j) o[j] = (bf16)s[j];
    *(bf16x8*)(out + i) = o;
}

// ---------------------------------------------------------------------------
// rowdot: y[c] = sum_k x[k] * Wt[c,k] (+ addv[c]).  One WAVE per output
// element, bf16x8 vector loads, shfl tree reduce.  grid (C/4), block 256.
// ---------------------------------------------------------------------------
__global__ __launch_bounds__(256) void rowdot_kernel(
    const void* __restrict__ x, const bf16* __restrict__ Wt,
    const void* __restrict__ addv, const int* __restrict__ flag, int xMode,
    float* __restrict__ y, int K)
{
    const bool raw32 = (flag[0] == 0);
    const bool x32   = (xMode == 0) || raw32;
    const int wave = threadIdx.x >> 6, lane = threadIdx.x & 63;
    const int c = blockIdx.x * 4 + wave;
    float s = 0.f;
    for (int k0 = lane * 8; k0 < K; k0 += 512) {
        bf16x8 w = *(const bf16x8*)(Wt + (size_t)c * K + k0);
        float xv[8];
        ldx8(x, (size_t)k0, x32, xv);
#pragma unroll
        for (int j = 0; j < 8; ++j) s += xv[j] * (float)w[j];
    }
#pragma unroll
    for (int off = 32; off; off >>= 1) s += __shfl_down(s, off);
    if (lane == 0) {
        float a = addv ? ldin(addv, c, raw32) : 0.f;
        y[c] = s + a;
    }
}

// out[b,h] = cbias[h] + sum_n softmax(sc[b,:])_n * gstar[b*PN+n, h]
// grid (PB), block 256, 4 h/thread.  Output dtype per flag.
__global__ __launch_bounds__(256) void context_kernel(
    const float* __restrict__ sc, const bf16* __restrict__ gstar,
    const float* __restrict__ cbias, const int* __restrict__ flag,
    void* __restrict__ out)
{
    const int b = blockIdx.x, tid = threadIdx.x;
    const int h = tid * 4;
    float e[PN];
    float mx = -1e30f;
    for (int n = 0; n < PN; ++n) mx = fmaxf(mx, sc[b * PN + n]);
    float sum = 0.f;
    for (int n = 0; n < PN; ++n) { e[n] = expf(sc[b * PN + n] - mx); sum += e[n]; }
    const float inv = 1.f / sum;
    f32x4 cb = *(const f32x4*)(cbias + h);
    float acc[4] = {cb[0], cb[1], cb[2], cb[3]};
    for (int n = 0; n < PN; ++n) {
        float al = e[n] * inv;
        bf16v4 g = *(const bf16v4*)(gstar + (size_t)(b * PN + n) * PH + h);
#pragma unroll
        for (int j = 0; j < 4; ++j) acc[j] += al * (float)g[j];
    }
    if (flag[0]) {
        bf16v4 o;
#pragma unroll
        for (int j = 0; j < 4; ++j) o[j] = (bf16)acc[j];
        *(bf16v4*)((bf16*)out + (size_t)b * PH + h) = o;
    } else {
        f32x4 o;
#pragma unroll
        for (int j = 0; j < 4; ++j) o[j] = acc[j];
        *(f32x4*)((float*)out + (size_t)b * PH + h) = o;
    }
}

// ---------------------------------------------------------------------------
extern "C" void kernel_launch(void* const* d_in, const int* in_sizes, int n_in,
                              void* d_out, int out_size, void* d_ws, size_t ws_size,
                              hipStream_t stream)
{
    const void* GF  = d_in[0];
    const void* s_t = d_in[1];
    const void* cov = d_in[2];
    const void* Wg  = d_in[3];
    const void* bg  = d_in[4];
    const void* Wgs = d_in[5];
    const void* bgs = d_in[6];
    const void* Wh  = d_in[7];
    const void* Ws  = d_in[8];
    const void* Wc  = d_in[9];
    const void* v   = d_in[10];
    (void)in_sizes; (void)n_in; (void)out_size; (void)ws_size;

    // ---- workspace plan (peak 132 MiB; lifetime-overlap) ----
    const size_t MB = 1u << 20;
    char* W = (char*)d_ws;
    bf16*  GFb    = (bf16*) (W + 0);               // 49 MiB   [S1-S5]
    bf16*  g_star = (bf16*) (W + 0);               // 12.25MiB [S5b-S8], over dead GFb
    int*   flag   = (int*)  (W + 52 * MB);
    float* tbias  = (float*)(W + 52 * MB + 4096);
    float* cbias  = (float*)(W + 52 * MB + 8192);
    float* sc     = (float*)(W + 52 * MB + 12288); // 25 KB
    bf16*  s_tb   = (bf16*) (W + 52 * MB + 262144);// 0.25 MiB
    bf16*  WsT    = (bf16*) (W + 53 * MB);         // 2 MiB    [S1-S6]
    bf16*  WhT    = (bf16*) (W + 55 * MB);         // 2 MiB    [S1-S7]
    float* sprojP = (float*)(W + 57 * MB);         // 2 MiB (4 planes) [S6-S7]
    bf16*  WgsT   = (bf16*) (W + 59 * MB);         // 8 MiB    [S1-S3]
    bf16*  WggsT  = (bf16*) (W + 59 * MB);         // 8 MiB    [S3b-S5], over dead WgsT
    bf16*  WggsP  = (bf16*) (W + 67 * MB);         // 32 MiB (4 planes) [S3-S3b]
    bf16*  gP     = (bf16*) (W + 67 * MB);         // 24.5 MiB (2 planes) [S5-S5b]
    bf16*  Wgb    = (bf16*) (W + 100 * MB);        // 32 MiB   [S1-S3]  peak = 132 MiB

    dim3 blk(256);

    // 0. dtype detect
    detect_kernel<<<dim3(1), blk, 0, stream>>>((const unsigned short*)GF, flag);

    // 1. fused conversions (GF, Wg, s_t -> bf16) + sc zeroing; batched
    //    transposes (Wgs, Wh, Ws).  20 -> 12 dispatches total this round:
    //    ~6-8 us/dispatch graph overhead was the largest unexplained cost.
    cvt3_kernel<<<dim3(2048), blk, 0, stream>>>(
        GF, (size_t)(PM1 * PG) / 2048, GFb,
        Wg, (size_t)(PG * PG) / 2048, Wgb,
        s_t, (size_t)(PB * PH) / 2048, s_tb,
        flag, sc, PB * PN);
    transpose3_kernel<<<dim3(1536), blk, 0, stream>>>(
        Wgs, WgsT, Wh, WhT, Ws, WsT, flag);

    // 2. cbias = bg@Wgs + bgs;  tbias = cbias@Wh
    rowdot_kernel<<<dim3(PH / 4), blk, 0, stream>>>(bg, WgsT, bgs, flag, 1, cbias, PG);
    rowdot_kernel<<<dim3(PA / 4), blk, 0, stream>>>(cbias, WhT, nullptr, flag, 0, tbias, PH);

    // 3. WggsT[H,G] = WgsT @ Wg^T  (split-K 4 -> 1024 blocks) + reduce4
    gemm_kernel<1><<<dim3(PG / 128, PH / 128, 4), blk, 0, stream>>>(
        WgsT, Wgb, nullptr, WggsP, PH, PG, PG, (PG / 64) / 4);
    reduce_kernel<4><<<dim3((PH * PG) / 2048), blk, 0, stream>>>(
        WggsP, WggsT, (size_t)PH * PG);

    // 5. g_star planes = GF @ Wggs  (split-K 2 -> 784 blocks) + reduce2
    gemm_kernel<1><<<dim3(PH / 128, PM1 / 128, 2), blk, 0, stream>>>(
        GFb, WggsT, nullptr, gP, PM1, PH, PG, (PG / 64) / 2);
    reduce_kernel<2><<<dim3((PM1 * PH) / 2048), blk, 0, stream>>>(
        gP, g_star, (size_t)PM1 * PH);

    // 6. sproj = s_t @ Ws   (split-K 4, fp32 planes; summed in epilogue)
    gemm_kernel<0><<<dim3(PA / 128, 1, 4), blk, 0, stream>>>(
        s_tb, WsT, sprojP, nullptr, PB, PA, PH, (PH / 64) / 4);

    // 7. fused t2-GEMM + scores -> sc  (no split-K; tanh needs full K sum)
    gemm_scores_kernel<<<dim3(PA / 128, PM1 / 128), blk, 0, stream>>>(
        g_star, WhT, sprojP, tbias, cov, Wc, v, flag, sc);

    // 8. context: softmax + weighted sum of g_star + cbias -> out
    context_kernel<<<dim3(PB), blk, 0, stream>>>(sc, g_star, cbias, flag, d_out);
}

// Round 6
// 439.468 us; speedup vs baseline: 1.0155x; 1.0155x over previous
//
#include <hip/hip_runtime.h>
#include <cstdint>
#include <cstddef>

typedef __bf16 bf16;
typedef __bf16 bf16x8 __attribute__((ext_vector_type(8)));
typedef __bf16 bf16v4 __attribute__((ext_vector_type(4)));
typedef float  f32x4  __attribute__((ext_vector_type(4)));

// Problem constants: B=128, N=49, G=4096, H=1024, A=1024
#define PB   128
#define PN   49
#define PG   4096
#define PH   1024
#define PA   1024
#define PM1  (PB * PN)   // 6272

// ---------------------------------------------------------------------------
// dtype detect: flag=1 -> bf16 inputs, 0 -> fp32.
// ---------------------------------------------------------------------------
__global__ __launch_bounds__(256) void detect_kernel(
    const unsigned short* __restrict__ raw, int* __restrict__ flag)
{
    __shared__ int cnt;
    if (threadIdx.x == 0) cnt = 0;
    __syncthreads();
    unsigned short u = raw[threadIdx.x];
    float x = __uint_as_float(((unsigned int)u) << 16);
    float a = fabsf(x);
    atomicAdd(&cnt, (a >= 1e-7f && a <= 128.f) ? 1 : 0);
    __syncthreads();
    if (threadIdx.x == 0) flag[0] = (cnt >= 200) ? 1 : 0;
}

__device__ __forceinline__ float ldin(const void* p, size_t i, bool in32) {
    return in32 ? ((const float*)p)[i] : (float)((const bf16*)p)[i];
}

// load 8 consecutive elems of x (fp32 or bf16) as float
__device__ __forceinline__ void ldx8(const void* x, size_t k0, bool in32, float* xv) {
    if (in32) {
        f32x4 lo = *(const f32x4*)((const float*)x + k0);
        f32x4 hi = *(const f32x4*)((const float*)x + k0 + 4);
#pragma unroll
        for (int j = 0; j < 4; ++j) { xv[j] = lo[j]; xv[4 + j] = hi[j]; }
    } else {
        bf16x8 v = *(const bf16x8*)((const bf16*)x + k0);
#pragma unroll
        for (int j = 0; j < 8; ++j) xv[j] = (float)v[j];
    }
}

// ---------------------------------------------------------------------------
// Fused 3-region cvt (fp32 -> bf16) + sc zeroing.
// R5 post-mortem: on the bf16-input bench this kernel was a pure 81 MiB
// memcpy costing 80 us (top dispatch).  Now: when flag=1 the consumers read
// the RAW inputs directly (alt-pointer select in gemm_kernel), so this
// kernel zeroes sc and EXITS.  The conversion loop only runs for fp32.
// ---------------------------------------------------------------------------
__global__ __launch_bounds__(256) void cvt3_kernel(
    const void* __restrict__ in0, size_t u0, bf16* __restrict__ o0,
    const void* __restrict__ in1, size_t u1, bf16* __restrict__ o1,
    const void* __restrict__ in2, size_t u2, bf16* __restrict__ o2,
    const int* __restrict__ flag, float* __restrict__ sc_zero, int sczn)
{
    if (blockIdx.x == 0) {
        for (int i = threadIdx.x; i < sczn; i += 256) sc_zero[i] = 0.f;
    }
    if (flag[0] == 1) return;   // bf16 inputs: zero-copy path
    const size_t total = u0 + u1 + u2;
    for (size_t u = blockIdx.x; u < total; u += gridDim.x) {
        const void* in; bf16* out; size_t rel;
        if (u < u0)            { in = in0; out = o0; rel = u; }
        else if (u < u0 + u1)  { in = in1; out = o1; rel = u - u0; }
        else                   { in = in2; out = o2; rel = u - u0 - u1; }
        size_t i = rel * 2048 + (size_t)threadIdx.x * 8;
        f32x4 lo = *(const f32x4*)((const float*)in + i);
        f32x4 hi = *(const f32x4*)((const float*)in + i + 4);
        bf16x8 o;
#pragma unroll
        for (int j = 0; j < 4; ++j) { o[j] = (bf16)lo[j]; o[4 + j] = (bf16)hi[j]; }
        *(bf16x8*)(out + i) = o;
    }
}

// ---------------------------------------------------------------------------
// GEMM: C[M,N] = A[M,K] @ Bt^T.  128x128 tile, BK=64, 4 waves,
// mfma 16x16x32 bf16.  Both operands bf16, staged via global_load_lds(16B)
// async DMA with (chunk+row)&7 source rotation (0 bank conflicts, verified).
// Aalt/Btalt: optional RAW input pointers — when flag=1 (bf16 inputs) the
// operand is read directly from the input buffer (zero-copy), skipping the
// ws conversion copy.  Wave-uniform select at entry, free in the K-loop.
// Bijective XCD-aware block swizzle (m204).  Split-K via bz plane.
// ---------------------------------------------------------------------------
template <int BF16OUT>
__global__ __launch_bounds__(256, 2) void gemm_kernel(
    const bf16* __restrict__ A, const bf16* __restrict__ Bt0,
    const void* __restrict__ Aalt, const void* __restrict__ Btalt,
    const int* __restrict__ flag,
    float* __restrict__ Cf, bf16* __restrict__ Cb,
    int M, int N, int K, int kTilesPerSplit)
{
    __shared__ __align__(16) bf16 lds[2 * 128 * 64];
    bf16* As  = lds;
    bf16* Bs0 = lds + 128 * 64;

    if (Aalt  && flag[0]) A   = (const bf16*)Aalt;
    if (Btalt && flag[0]) Bt0 = (const bf16*)Btalt;

    const int gx = gridDim.x, gy = gridDim.y;
    const int nwg = gx * gy * (int)gridDim.z;
    int flat = blockIdx.x + gx * (blockIdx.y + gy * blockIdx.z);
    {
        const int q8 = nwg >> 3, r8 = nwg & 7;
        const int xcd = flat & 7, sub = flat >> 3;
        flat = (xcd < r8 ? xcd * (q8 + 1) : r8 * (q8 + 1) + (xcd - r8) * q8) + sub;
    }
    const int bx  = flat % gx;
    const int byz = flat / gx;
    const int by  = byz % gy;
    const int bz  = byz / gy;

    const int tid  = threadIdx.x;
    const int m0   = by * 128;
    const int n0   = bx * 128;
    const int kt0  = bz * kTilesPerSplit;

    const int wave = tid >> 6;
    const int lane = tid & 63;
    const int wm   = (wave >> 1) * 64;
    const int wn   = (wave & 1) * 64;
    const int lm   = lane & 15;
    const int q    = lane >> 4;

    f32x4 acc[4][4];
#pragma unroll
    for (int i = 0; i < 4; ++i)
#pragma unroll
        for (int j = 0; j < 4; ++j) acc[i][j] = (f32x4)0.0f;

    for (int kt = 0; kt < kTilesPerSplit; ++kt) {
        const int k0 = (kt0 + kt) * 64;
#pragma unroll
        for (int it = 0; it < 4; ++it) {
            int p   = it * 256 + tid;
            int row = p >> 3;
            int lc  = ((p & 7) - row) & 7;
            size_t offB = (size_t)(n0 + row) * K + k0 + lc * 8;
            __builtin_amdgcn_global_load_lds((void*)(Bt0 + offB), (void*)(Bs0 + p * 8), 16, 0, 0);
            size_t offA = (size_t)(m0 + row) * K + k0 + lc * 8;
            __builtin_amdgcn_global_load_lds((void*)(A + offA), (void*)(As + p * 8), 16, 0, 0);
        }
        __syncthreads();

#pragma unroll
        for (int s = 0; s < 2; ++s) {
            bf16x8 af[4], bf0[4];
            const int c = s * 4 + q;
#pragma unroll
            for (int mi = 0; mi < 4; ++mi) {
                int row  = wm + mi * 16 + lm;
                int slot = row * 8 + ((c + row) & 7);
                af[mi] = *(const bf16x8*)(As + slot * 8);
            }
#pragma unroll
            for (int ni = 0; ni < 4; ++ni) {
                int row  = wn + ni * 16 + lm;
                int slot = row * 8 + ((c + row) & 7);
                bf0[ni] = *(const bf16x8*)(Bs0 + slot * 8);
            }
#pragma unroll
            for (int mi = 0; mi < 4; ++mi)
#pragma unroll
                for (int ni = 0; ni < 4; ++ni)
                    acc[mi][ni] = __builtin_amdgcn_mfma_f32_16x16x32_bf16(
                        af[mi], bf0[ni], acc[mi][ni], 0, 0, 0);
        }
        __syncthreads();
    }

#pragma unroll
    for (int mi = 0; mi < 4; ++mi)
#pragma unroll
        for (int ni = 0; ni < 4; ++ni)
#pragma unroll
            for (int r = 0; r < 4; ++r) {
                int row = m0 + wm + mi * 16 + q * 4 + r;
                int col = n0 + wn + ni * 16 + lm;
                if (BF16OUT)
                    Cb[(size_t)bz * M * N + (size_t)row * N + col] = (bf16)acc[mi][ni][r];
                else
                    Cf[(size_t)bz * M * N + (size_t)row * N + col] = acc[mi][ni][r];
            }
}

// ---------------------------------------------------------------------------
// Fused t2-GEMM + scores: sc[m] += sum_col v[col]*tanh(t2[m,col] + sproj +
// tbias + cov*Wc).  A = g_star [PM1,PH], Bt = WhT [PA,PH], no split-K (tanh
// needs the full K sum).  Epilogue: tanh + 16-lane shuffle row-reduce + one
// atomicAdd per row.  grid (PA/128, PM1/128); sc pre-zeroed in cvt3.
// ---------------------------------------------------------------------------
__global__ __launch_bounds__(256, 2) void gemm_scores_kernel(
    const bf16* __restrict__ A, const bf16* __restrict__ Bt0,
    const float* __restrict__ sprojP, const float* __restrict__ tbias,
    const void* __restrict__ cov, const void* __restrict__ Wc,
    const void* __restrict__ v, const int* __restrict__ flag,
    float* __restrict__ sc)
{
    constexpr int K = PH;
    __shared__ __align__(16) bf16 lds[2 * 128 * 64];
    bf16* As  = lds;
    bf16* Bs0 = lds + 128 * 64;

    const int gx = gridDim.x, gy = gridDim.y;
    const int nwg = gx * gy;
    int flat = blockIdx.x + gx * blockIdx.y;
    {
        const int q8 = nwg >> 3, r8 = nwg & 7;
        const int xcd = flat & 7, sub = flat >> 3;
        flat = (xcd < r8 ? xcd * (q8 + 1) : r8 * (q8 + 1) + (xcd - r8) * q8) + sub;
    }
    const int bx = flat % gx;
    const int by = flat / gx;

    const int tid  = threadIdx.x;
    const int m0   = by * 128;
    const int n0   = bx * 128;

    const int wave = tid >> 6;
    const int lane = tid & 63;
    const int wm   = (wave >> 1) * 64;
    const int wn   = (wave & 1) * 64;
    const int lm   = lane & 15;
    const int q    = lane >> 4;

    f32x4 acc[4][4];
#pragma unroll
    for (int i = 0; i < 4; ++i)
#pragma unroll
        for (int j = 0; j < 4; ++j) acc[i][j] = (f32x4)0.0f;

    for (int kt = 0; kt < K / 64; ++kt) {
        const int k0 = kt * 64;
#pragma unroll
        for (int it = 0; it < 4; ++it) {
            int p   = it * 256 + tid;
            int row = p >> 3;
            int lc  = ((p & 7) - row) & 7;
            size_t offB = (size_t)(n0 + row) * K + k0 + lc * 8;
            __builtin_amdgcn_global_load_lds((void*)(Bt0 + offB), (void*)(Bs0 + p * 8), 16, 0, 0);
            size_t offA = (size_t)(m0 + row) * K + k0 + lc * 8;
            __builtin_amdgcn_global_load_lds((void*)(A + offA), (void*)(As + p * 8), 16, 0, 0);
        }
        __syncthreads();

#pragma unroll
        for (int s = 0; s < 2; ++s) {
            bf16x8 af[4], bf0[4];
            const int c = s * 4 + q;
#pragma unroll
            for (int mi = 0; mi < 4; ++mi) {
                int row  = wm + mi * 16 + lm;
                int slot = row * 8 + ((c + row) & 7);
                af[mi] = *(const bf16x8*)(As + slot * 8);
            }
#pragma unroll
            for (int ni = 0; ni < 4; ++ni) {
                int row  = wn + ni * 16 + lm;
                int slot = row * 8 + ((c + row) & 7);
                bf0[ni] = *(const bf16x8*)(Bs0 + slot * 8);
            }
#pragma unroll
            for (int mi = 0; mi < 4; ++mi)
#pragma unroll
                for (int ni = 0; ni < 4; ++ni)
                    acc[mi][ni] = __builtin_amdgcn_mfma_f32_16x16x32_bf16(
                        af[mi], bf0[ni], acc[mi][ni], 0, 0, 0);
        }
        __syncthreads();
    }

    // ---- fused scores epilogue ----
    const bool in32 = (flag[0] == 0);
    float tb[4], wc4[4], vv[4];
#pragma unroll
    for (int ni = 0; ni < 4; ++ni) {
        int col = n0 + wn + ni * 16 + lm;
        tb[ni]  = tbias[col];
        wc4[ni] = ldin(Wc, col, in32);
        vv[ni]  = ldin(v, col, in32);
    }
#pragma unroll
    for (int mi = 0; mi < 4; ++mi)
#pragma unroll
        for (int r = 0; r < 4; ++r) {
            int grow = m0 + wm + mi * 16 + q * 4 + r;
            int b    = grow / PN;
            float cv = ldin(cov, grow, in32);
            const float* sp0 = sprojP + (size_t)b * PA;
            float rowsum = 0.f;
#pragma unroll
            for (int ni = 0; ni < 4; ++ni) {
                int col = n0 + wn + ni * 16 + lm;
                float sp = sp0[col] + sp0[PB * PA + col]
                         + sp0[2 * PB * PA + col] + sp0[3 * PB * PA + col];
                float val = acc[mi][ni][r] + sp + tb[ni] + cv * wc4[ni];
                rowsum += vv[ni] * tanhf(val);
            }
#pragma unroll
            for (int off = 1; off < 16; off <<= 1)
                rowsum += __shfl_xor(rowsum, off);
            if (lm == 0) atomicAdd(&sc[grow], rowsum);
        }
}

// ---------------------------------------------------------------------------
// Batched transpose of the 3 weight inputs (raw dtype -> bf16 [C,R]).
// blocks 0..1023: Wgs [PG,PH]; 1024..1279: Wh [PH,PA]; 1280..1535: Ws.
// ---------------------------------------------------------------------------
__global__ __launch_bounds__(256) void transpose3_kernel(
    const void* __restrict__ inA, bf16* __restrict__ outA,
    const void* __restrict__ inB, bf16* __restrict__ outB,
    const void* __restrict__ inC, bf16* __restrict__ outC,
    const int* __restrict__ flag)
{
    __shared__ bf16 tile[64][65];
    const bool in32 = (flag[0] == 0);
    const int bid = blockIdx.x;
    const void* in; bf16* out; int R, C, bx, by;
    if (bid < 1024)      { in = inA; out = outA; R = PG; C = PH; bx = bid & 15; by = bid >> 4; }
    else if (bid < 1280) { int t = bid - 1024; in = inB; out = outB; R = PH; C = PA; bx = t & 15; by = t >> 4; }
    else                 { int t = bid - 1280; in = inC; out = outC; R = PH; C = PA; bx = t & 15; by = t >> 4; }
    const int r0 = by * 64, c0 = bx * 64;
    const int tx = threadIdx.x & 15, ty = threadIdx.x >> 4;
#pragma unroll
    for (int it = 0; it < 4; ++it) {
        int r = it * 16 + ty;
        size_t base = (size_t)(r0 + r) * C + c0 + tx * 4;
        if (in32) {
            f32x4 vv = *(const f32x4*)((const float*)in + base);
#pragma unroll
            for (int i = 0; i < 4; ++i) tile[r][tx * 4 + i] = (bf16)vv[i];
        } else {
            bf16v4 vv = *(const bf16v4*)((const bf16*)in + base);
#pragma unroll
            for (int i = 0; i < 4; ++i) tile[r][tx * 4 + i] = vv[i];
        }
    }
    __syncthreads();
#pragma unroll
    for (int it = 0; it < 4; ++it) {
        int c = it * 16 + ty;
        bf16v4 vv;
#pragma unroll
        for (int i = 0; i < 4; ++i) vv[i] = tile[tx * 4 + i][c];
        *(bf16v4*)(out + (size_t)(c0 + c) * R + r0 + tx * 4) = vv;
    }
}

// elementwise reduce of PLANES bf16 planes -> single bf16, 8 elems/thread
template <int PLANES>
__global__ __launch_bounds__(256) void reduce_kernel(
    const bf16* __restrict__ in, bf16* __restrict__ out, size_t n)
{
    size_t i = ((size_t)blockIdx.x * 256 + threadIdx.x) * 8;
    float s[8] = {0,0,0,0,0,0,0,0};
#pragma unroll
    for (int p = 0; p < PLANES; ++p) {
        bf16x8 v = *(const bf16x8*)(in + (size_t)p * n + i);
#pragma unroll
        for (int j = 0; j < 8; ++j) s[j] += (float)v[j];
    }
    bf16x8 o;
#pragma unroll
    for (int j = 0; j < 8; ++j) o[j] = (bf16)s[j];
    *(bf16x8*)(out + i) = o;
}

// ---------------------------------------------------------------------------
// rowdot: y[c] = sum_k x[k] * Wt[c,k] (+ addv[c]).  One WAVE per output
// element, bf16x8 vector loads, shfl tree reduce.  grid (C/4), block 256.
// ---------------------------------------------------------------------------
__global__ __launch_bounds__(256) void rowdot_kernel(
    const void* __restrict__ x, const bf16* __restrict__ Wt,
    const void* __restrict__ addv, const int* __restrict__ flag, int xMode,
    float* __restrict__ y, int K)
{
    const bool raw32 = (flag[0] == 0);
    const bool x32   = (xMode == 0) || raw32;
    const int wave = threadIdx.x >> 6, lane = threadIdx.x & 63;
    const int c = blockIdx.x * 4 + wave;
    float s = 0.f;
    for (int k0 = lane * 8; k0 < K; k0 += 512) {
        bf16x8 w = *(const bf16x8*)(Wt + (size_t)c * K + k0);
        float xv[8];
        ldx8(x, (size_t)k0, x32, xv);
#pragma unroll
        for (int j = 0; j < 8; ++j) s += xv[j] * (float)w[j];
    }
#pragma unroll
    for (int off = 32; off; off >>= 1) s += __shfl_down(s, off);
    if (lane == 0) {
        float a = addv ? ldin(addv, c, raw32) : 0.f;
        y[c] = s + a;
    }
}

// out[b,h] = cbias[h] + sum_n softmax(sc[b,:])_n * gstar[b*PN+n, h]
// grid (PB), block 256, 4 h/thread.  Output dtype per flag.
__global__ __launch_bounds__(256) void context_kernel(
    const float* __restrict__ sc, const bf16* __restrict__ gstar,
    const float* __restrict__ cbias, const int* __restrict__ flag,
    void* __restrict__ out)
{
    const int b = blockIdx.x, tid = threadIdx.x;
    const int h = tid * 4;
    float e[PN];
    float mx = -1e30f;
    for (int n = 0; n < PN; ++n) mx = fmaxf(mx, sc[b * PN + n]);
    float sum = 0.f;
    for (int n = 0; n < PN; ++n) { e[n] = expf(sc[b * PN + n] - mx); sum += e[n]; }
    const float inv = 1.f / sum;
    f32x4 cb = *(const f32x4*)(cbias + h);
    float acc[4] = {cb[0], cb[1], cb[2], cb[3]};
    for (int n = 0; n < PN; ++n) {
        float al = e[n] * inv;
        bf16v4 g = *(const bf16v4*)(gstar + (size_t)(b * PN + n) * PH + h);
#pragma unroll
        for (int j = 0; j < 4; ++j) acc[j] += al * (float)g[j];
    }
    if (flag[0]) {
        bf16v4 o;
#pragma unroll
        for (int j = 0; j < 4; ++j) o[j] = (bf16)acc[j];
        *(bf16v4*)((bf16*)out + (size_t)b * PH + h) = o;
    } else {
        f32x4 o;
#pragma unroll
        for (int j = 0; j < 4; ++j) o[j] = acc[j];
        *(f32x4*)((float*)out + (size_t)b * PH + h) = o;
    }
}

// ---------------------------------------------------------------------------
extern "C" void kernel_launch(void* const* d_in, const int* in_sizes, int n_in,
                              void* d_out, int out_size, void* d_ws, size_t ws_size,
                              hipStream_t stream)
{
    const void* GF  = d_in[0];
    const void* s_t = d_in[1];
    const void* cov = d_in[2];
    const void* Wg  = d_in[3];
    const void* bg  = d_in[4];
    const void* Wgs = d_in[5];
    const void* bgs = d_in[6];
    const void* Wh  = d_in[7];
    const void* Ws  = d_in[8];
    const void* Wc  = d_in[9];
    const void* v   = d_in[10];
    (void)in_sizes; (void)n_in; (void)out_size; (void)ws_size;

    // ---- workspace plan (peak 132 MiB; lifetime-overlap, same as R4) ----
    const size_t MB = 1u << 20;
    char* W = (char*)d_ws;
    bf16*  GFb    = (bf16*) (W + 0);               // 49 MiB   [S1-S5, fp32 path only]
    bf16*  g_star = (bf16*) (W + 0);               // 12.25MiB [S5b-S8], over dead GFb
    int*   flag   = (int*)  (W + 52 * MB);
    float* tbias  = (float*)(W + 52 * MB + 4096);
    float* cbias  = (float*)(W + 52 * MB + 8192);
    float* sc     = (float*)(W + 52 * MB + 12288); // 25 KB
    bf16*  s_tb   = (bf16*) (W + 52 * MB + 262144);// 0.25 MiB [fp32 path only]
    bf16*  WsT    = (bf16*) (W + 53 * MB);         // 2 MiB    [S1-S6]
    bf16*  WhT    = (bf16*) (W + 55 * MB);         // 2 MiB    [S1-S7]
    float* sprojP = (float*)(W + 57 * MB);         // 2 MiB (4 planes) [S6-S7]
    bf16*  WgsT   = (bf16*) (W + 59 * MB);         // 8 MiB    [S1-S3]
    bf16*  WggsT  = (bf16*) (W + 59 * MB);         // 8 MiB    [S3b-S5], over dead WgsT
    bf16*  WggsP  = (bf16*) (W + 67 * MB);         // 32 MiB (4 planes) [S3-S3b]
    bf16*  gP     = (bf16*) (W + 67 * MB);         // 49 MiB (4 planes) [S5-S5b]
    bf16*  Wgb    = (bf16*) (W + 100 * MB);        // 32 MiB   [S1-S3, fp32 path] peak = 132 MiB

    dim3 blk(256);

    // 0. dtype detect
    detect_kernel<<<dim3(1), blk, 0, stream>>>((const unsigned short*)GF, flag);

    // 1. cvt (fp32 path only; bf16 path zero-copies via alt pointers) + sc
    //    zeroing; batched transposes (always needed — layout change).
    cvt3_kernel<<<dim3(2048), blk, 0, stream>>>(
        GF, (size_t)(PM1 * PG) / 2048, GFb,
        Wg, (size_t)(PG * PG) / 2048, Wgb,
        s_t, (size_t)(PB * PH) / 2048, s_tb,
        flag, sc, PB * PN);
    transpose3_kernel<<<dim3(1536), blk, 0, stream>>>(
        Wgs, WgsT, Wh, WhT, Ws, WsT, flag);

    // 2. cbias = bg@Wgs + bgs;  tbias = cbias@Wh
    rowdot_kernel<<<dim3(PH / 4), blk, 0, stream>>>(bg, WgsT, bgs, flag, 1, cbias, PG);
    rowdot_kernel<<<dim3(PA / 4), blk, 0, stream>>>(cbias, WhT, nullptr, flag, 0, tbias, PH);

    // 3. WggsT[H,G] = WgsT @ Wg^T  (split-K 4 -> 1024 blocks) + reduce4
    //    Bt = raw Wg directly when bf16 (zero-copy), else the cvt'd Wgb.
    gemm_kernel<1><<<dim3(PG / 128, PH / 128, 4), blk, 0, stream>>>(
        WgsT, Wgb, nullptr, Wg, flag, nullptr, WggsP, PH, PG, PG, (PG / 64) / 4);
    reduce_kernel<4><<<dim3((PH * PG) / 2048), blk, 0, stream>>>(
        WggsP, WggsT, (size_t)PH * PG);

    // 5. g_star planes = GF @ Wggs  (split-K 4 -> 1568 blocks; R5's split-K 2
    //    measured slower 79.6 vs 71-74) + reduce4.  A = raw GF when bf16.
    gemm_kernel<1><<<dim3(PH / 128, PM1 / 128, 4), blk, 0, stream>>>(
        GFb, WggsT, GF, nullptr, flag, nullptr, gP, PM1, PH, PG, (PG / 64) / 4);
    reduce_kernel<4><<<dim3((PM1 * PH) / 2048), blk, 0, stream>>>(
        gP, g_star, (size_t)PM1 * PH);

    // 6. sproj = s_t @ Ws   (split-K 4, fp32 planes; summed in epilogue)
    gemm_kernel<0><<<dim3(PA / 128, 1, 4), blk, 0, stream>>>(
        s_tb, WsT, s_t, nullptr, flag, sprojP, nullptr, PB, PA, PH, (PH / 64) / 4);

    // 7. fused t2-GEMM + scores -> sc  (no split-K; tanh needs full K sum)
    gemm_scores_kernel<<<dim3(PA / 128, PM1 / 128), blk, 0, stream>>>(
        g_star, WhT, sprojP, tbias, cov, Wc, v, flag, sc);

    // 8. context: softmax + weighted sum of g_star + cbias -> out
    context_kernel<<<dim3(PB), blk, 0, stream>>>(sc, g_star, cbias, flag, d_out);
}

// Round 7
// 436.906 us; speedup vs baseline: 1.0215x; 1.0059x over previous
//
#include <hip/hip_runtime.h>
#include <cstdint>
#include <cstddef>

typedef __bf16 bf16;
typedef __bf16 bf16x8 __attribute__((ext_vector_type(8)));
typedef __bf16 bf16v4 __attribute__((ext_vector_type(4)));
typedef float  f32x4  __attribute__((ext_vector_type(4)));

// Problem constants: B=128, N=49, G=4096, H=1024, A=1024
#define PB   128
#define PN   49
#define PG   4096
#define PH   1024
#define PA   1024
#define PM1  (PB * PN)   // 6272

// cvt unit bookkeeping (unit = 2048 elems = 256 thr x 8)
#define U0   ((size_t)(PM1 * PG) / 2048)   // GF units   = 12544
#define U1   ((size_t)(PG * PG) / 2048)    // Wg units   = 8192
#define U2   ((size_t)(PB * PH) / 2048)    // s_t units  = 64
#define NCVT 2048                           // cvt blocks
#define NTRP 1536                           // transpose blocks

__device__ __forceinline__ float ldin(const void* p, size_t i, bool in32) {
    return in32 ? ((const float*)p)[i] : (float)((const bf16*)p)[i];
}

// load 8 consecutive elems of x (fp32 or bf16) as float
__device__ __forceinline__ void ldx8(const void* x, size_t k0, bool in32, float* xv) {
    if (in32) {
        f32x4 lo = *(const f32x4*)((const float*)x + k0);
        f32x4 hi = *(const f32x4*)((const float*)x + k0 + 4);
#pragma unroll
        for (int j = 0; j < 4; ++j) { xv[j] = lo[j]; xv[4 + j] = hi[j]; }
    } else {
        bf16x8 v = *(const bf16x8*)((const bf16*)x + k0);
#pragma unroll
        for (int j = 0; j < 8; ++j) xv[j] = (float)v[j];
    }
}

// ---------------------------------------------------------------------------
// prep: merged {dtype self-detect, fp32->bf16 cvt of GF/Wg/s_t, 3-way weight
// transpose, sc zeroing} in ONE dispatch.
// R6 post-mortem: inputs are fp32 (in_npz=181MB; cvt WRITE=81.3MiB bf16);
// cvt is mandatory and was 83us at ~3.1TB/s (latency-serialized 1-unit loop)
// plus detect+transpose dispatches.  Now: every block self-detects from
// GF[0..255] (L2-hit, no cross-block dep); blocks [0,NCVT) run the cvt with
// a 4-unit manual unroll (4 independent 32B loads in flight -> target
// ~4.5-5TB/s); blocks [NCVT,NCVT+NTRP) do the 3 weight transposes.
// ---------------------------------------------------------------------------
__global__ __launch_bounds__(256) void prep_kernel(
    const void* __restrict__ GF, const void* __restrict__ Wg,
    const void* __restrict__ s_t, const void* __restrict__ Wgs,
    const void* __restrict__ Wh, const void* __restrict__ Ws,
    bf16* __restrict__ GFb, bf16* __restrict__ Wgb, bf16* __restrict__ s_tb,
    bf16* __restrict__ WgsT, bf16* __restrict__ WhT, bf16* __restrict__ WsT,
    int* __restrict__ flag, float* __restrict__ sc_zero, int sczn)
{
    __shared__ bf16 tile[64][65];
    __shared__ int cntS;
    const int tid = threadIdx.x;
    const int bid = blockIdx.x;

    // ---- per-block self-detect (same heuristic as the old detect_kernel) ----
    if (tid == 0) cntS = 0;
    __syncthreads();
    {
        unsigned short u = ((const unsigned short*)GF)[tid];
        float x = __uint_as_float(((unsigned int)u) << 16);
        float a = fabsf(x);
        atomicAdd(&cntS, (a >= 1e-7f && a <= 128.f) ? 1 : 0);
    }
    __syncthreads();
    const bool isbf16 = (cntS >= 200);
    const bool in32   = !isbf16;

    if (bid == 0) {
        if (tid == 0) flag[0] = isbf16 ? 1 : 0;
        for (int i = tid; i < sczn; i += 256) sc_zero[i] = 0.f;
    }

    if (bid < NCVT) {
        // ---- cvt region (fp32 path only; bf16 inputs are zero-copied) ----
        if (isbf16) return;
        const size_t total = U0 + U1 + U2;
        for (size_t u = bid; u < total; u += (size_t)NCVT * 4) {
            const float* pin[4]; bf16* pout[4]; bool val[4];
            f32x4 lo[4], hi[4];
#pragma unroll
            for (int j = 0; j < 4; ++j) {
                size_t uu = u + (size_t)j * NCVT;
                val[j] = (uu < total);
                if (val[j]) {
                    const float* pi; bf16* po;
                    if (uu < U0)            { pi = (const float*)GF + uu * 2048;          po = GFb + uu * 2048; }
                    else if (uu < U0 + U1)  { size_t r = uu - U0;      pi = (const float*)Wg + r * 2048;  po = Wgb + r * 2048; }
                    else                    { size_t r = uu - U0 - U1; pi = (const float*)s_t + r * 2048; po = s_tb + r * 2048; }
                    pi += (size_t)tid * 8; po += (size_t)tid * 8;
                    pin[j] = pi; pout[j] = po;
                    lo[j] = *(const f32x4*)pi;
                    hi[j] = *(const f32x4*)(pi + 4);
                }
            }
#pragma unroll
            for (int j = 0; j < 4; ++j) {
                if (val[j]) {
                    bf16x8 o;
#pragma unroll
                    for (int k = 0; k < 4; ++k) { o[k] = (bf16)lo[j][k]; o[4 + k] = (bf16)hi[j][k]; }
                    *(bf16x8*)pout[j] = o;
                }
            }
        }
        return;
    }

    // ---- transpose region (always runs; layout change needed either way) ----
    const int t = bid - NCVT;
    const void* in; bf16* out; int R, C, bx, by;
    if (t < 1024)      { in = Wgs; out = WgsT; R = PG; C = PH; bx = t & 15; by = t >> 4; }
    else if (t < 1280) { int tt = t - 1024; in = Wh; out = WhT; R = PH; C = PA; bx = tt & 15; by = tt >> 4; }
    else               { int tt = t - 1280; in = Ws; out = WsT; R = PH; C = PA; bx = tt & 15; by = tt >> 4; }
    const int r0 = by * 64, c0 = bx * 64;
    const int tx = tid & 15, ty = tid >> 4;
#pragma unroll
    for (int it = 0; it < 4; ++it) {
        int r = it * 16 + ty;
        size_t base = (size_t)(r0 + r) * C + c0 + tx * 4;
        if (in32) {
            f32x4 vv = *(const f32x4*)((const float*)in + base);
#pragma unroll
            for (int i = 0; i < 4; ++i) tile[r][tx * 4 + i] = (bf16)vv[i];
        } else {
            bf16v4 vv = *(const bf16v4*)((const bf16*)in + base);
#pragma unroll
            for (int i = 0; i < 4; ++i) tile[r][tx * 4 + i] = vv[i];
        }
    }
    __syncthreads();
#pragma unroll
    for (int it = 0; it < 4; ++it) {
        int c = it * 16 + ty;
        bf16v4 vv;
#pragma unroll
        for (int i = 0; i < 4; ++i) vv[i] = tile[tx * 4 + i][c];
        *(bf16v4*)(out + (size_t)(c0 + c) * R + r0 + tx * 4) = vv;
    }
}

// ---------------------------------------------------------------------------
// GEMM: C[M,N] = A[M,K] @ Bt^T.  128x128 tile, BK=64, 4 waves,
// mfma 16x16x32 bf16.  Both operands bf16, staged via global_load_lds(16B)
// async DMA with (chunk+row)&7 source rotation (0 bank conflicts, verified).
// Aalt/Btalt: optional RAW input pointers used when flag=1 (bf16 inputs).
// Bijective XCD-aware block swizzle (m204).  Split-K via bz plane.
// ---------------------------------------------------------------------------
template <int BF16OUT>
__global__ __launch_bounds__(256, 2) void gemm_kernel(
    const bf16* __restrict__ A, const bf16* __restrict__ Bt0,
    const void* __restrict__ Aalt, const void* __restrict__ Btalt,
    const int* __restrict__ flag,
    float* __restrict__ Cf, bf16* __restrict__ Cb,
    int M, int N, int K, int kTilesPerSplit)
{
    __shared__ __align__(16) bf16 lds[2 * 128 * 64];
    bf16* As  = lds;
    bf16* Bs0 = lds + 128 * 64;

    if (Aalt  && flag[0]) A   = (const bf16*)Aalt;
    if (Btalt && flag[0]) Bt0 = (const bf16*)Btalt;

    const int gx = gridDim.x, gy = gridDim.y;
    const int nwg = gx * gy * (int)gridDim.z;
    int flat = blockIdx.x + gx * (blockIdx.y + gy * blockIdx.z);
    {
        const int q8 = nwg >> 3, r8 = nwg & 7;
        const int xcd = flat & 7, sub = flat >> 3;
        flat = (xcd < r8 ? xcd * (q8 + 1) : r8 * (q8 + 1) + (xcd - r8) * q8) + sub;
    }
    const int bx  = flat % gx;
    const int byz = flat / gx;
    const int by  = byz % gy;
    const int bz  = byz / gy;

    const int tid  = threadIdx.x;
    const int m0   = by * 128;
    const int n0   = bx * 128;
    const int kt0  = bz * kTilesPerSplit;

    const int wave = tid >> 6;
    const int lane = tid & 63;
    const int wm   = (wave >> 1) * 64;
    const int wn   = (wave & 1) * 64;
    const int lm   = lane & 15;
    const int q    = lane >> 4;

    f32x4 acc[4][4];
#pragma unroll
    for (int i = 0; i < 4; ++i)
#pragma unroll
        for (int j = 0; j < 4; ++j) acc[i][j] = (f32x4)0.0f;

    for (int kt = 0; kt < kTilesPerSplit; ++kt) {
        const int k0 = (kt0 + kt) * 64;
#pragma unroll
        for (int it = 0; it < 4; ++it) {
            int p   = it * 256 + tid;
            int row = p >> 3;
            int lc  = ((p & 7) - row) & 7;
            size_t offB = (size_t)(n0 + row) * K + k0 + lc * 8;
            __builtin_amdgcn_global_load_lds((void*)(Bt0 + offB), (void*)(Bs0 + p * 8), 16, 0, 0);
            size_t offA = (size_t)(m0 + row) * K + k0 + lc * 8;
            __builtin_amdgcn_global_load_lds((void*)(A + offA), (void*)(As + p * 8), 16, 0, 0);
        }
        __syncthreads();

#pragma unroll
        for (int s = 0; s < 2; ++s) {
            bf16x8 af[4], bf0[4];
            const int c = s * 4 + q;
#pragma unroll
            for (int mi = 0; mi < 4; ++mi) {
                int row  = wm + mi * 16 + lm;
                int slot = row * 8 + ((c + row) & 7);
                af[mi] = *(const bf16x8*)(As + slot * 8);
            }
#pragma unroll
            for (int ni = 0; ni < 4; ++ni) {
                int row  = wn + ni * 16 + lm;
                int slot = row * 8 + ((c + row) & 7);
                bf0[ni] = *(const bf16x8*)(Bs0 + slot * 8);
            }
#pragma unroll
            for (int mi = 0; mi < 4; ++mi)
#pragma unroll
                for (int ni = 0; ni < 4; ++ni)
                    acc[mi][ni] = __builtin_amdgcn_mfma_f32_16x16x32_bf16(
                        af[mi], bf0[ni], acc[mi][ni], 0, 0, 0);
        }
        __syncthreads();
    }

#pragma unroll
    for (int mi = 0; mi < 4; ++mi)
#pragma unroll
        for (int ni = 0; ni < 4; ++ni)
#pragma unroll
            for (int r = 0; r < 4; ++r) {
                int row = m0 + wm + mi * 16 + q * 4 + r;
                int col = n0 + wn + ni * 16 + lm;
                if (BF16OUT)
                    Cb[(size_t)bz * M * N + (size_t)row * N + col] = (bf16)acc[mi][ni][r];
                else
                    Cf[(size_t)bz * M * N + (size_t)row * N + col] = acc[mi][ni][r];
            }
}

// ---------------------------------------------------------------------------
// Fused t2-GEMM + scores: sc[m] += sum_col v[col]*tanh(t2[m,col] + sproj +
// tbias + cov*Wc).  A = g_star [PM1,PH], Bt = WhT [PA,PH], no split-K (tanh
// needs the full K sum).  Epilogue: tanh + 16-lane shuffle row-reduce + one
// atomicAdd per row.  grid (PA/128, PM1/128); sc pre-zeroed in prep.
// ---------------------------------------------------------------------------
__global__ __launch_bounds__(256, 2) void gemm_scores_kernel(
    const bf16* __restrict__ A, const bf16* __restrict__ Bt0,
    const float* __restrict__ sprojP, const float* __restrict__ tbias,
    const void* __restrict__ cov, const void* __restrict__ Wc,
    const void* __restrict__ v, const int* __restrict__ flag,
    float* __restrict__ sc)
{
    constexpr int K = PH;
    __shared__ __align__(16) bf16 lds[2 * 128 * 64];
    bf16* As  = lds;
    bf16* Bs0 = lds + 128 * 64;

    const int gx = gridDim.x, gy = gridDim.y;
    const int nwg = gx * gy;
    int flat = blockIdx.x + gx * blockIdx.y;
    {
        const int q8 = nwg >> 3, r8 = nwg & 7;
        const int xcd = flat & 7, sub = flat >> 3;
        flat = (xcd < r8 ? xcd * (q8 + 1) : r8 * (q8 + 1) + (xcd - r8) * q8) + sub;
    }
    const int bx = flat % gx;
    const int by = flat / gx;

    const int tid  = threadIdx.x;
    const int m0   = by * 128;
    const int n0   = bx * 128;

    const int wave = tid >> 6;
    const int lane = tid & 63;
    const int wm   = (wave >> 1) * 64;
    const int wn   = (wave & 1) * 64;
    const int lm   = lane & 15;
    const int q    = lane >> 4;

    f32x4 acc[4][4];
#pragma unroll
    for (int i = 0; i < 4; ++i)
#pragma unroll
        for (int j = 0; j < 4; ++j) acc[i][j] = (f32x4)0.0f;

    for (int kt = 0; kt < K / 64; ++kt) {
        const int k0 = kt * 64;
#pragma unroll
        for (int it = 0; it < 4; ++it) {
            int p   = it * 256 + tid;
            int row = p >> 3;
            int lc  = ((p & 7) - row) & 7;
            size_t offB = (size_t)(n0 + row) * K + k0 + lc * 8;
            __builtin_amdgcn_global_load_lds((void*)(Bt0 + offB), (void*)(Bs0 + p * 8), 16, 0, 0);
            size_t offA = (size_t)(m0 + row) * K + k0 + lc * 8;
            __builtin_amdgcn_global_load_lds((void*)(A + offA), (void*)(As + p * 8), 16, 0, 0);
        }
        __syncthreads();

#pragma unroll
        for (int s = 0; s < 2; ++s) {
            bf16x8 af[4], bf0[4];
            const int c = s * 4 + q;
#pragma unroll
            for (int mi = 0; mi < 4; ++mi) {
                int row  = wm + mi * 16 + lm;
                int slot = row * 8 + ((c + row) & 7);
                af[mi] = *(const bf16x8*)(As + slot * 8);
            }
#pragma unroll
            for (int ni = 0; ni < 4; ++ni) {
                int row  = wn + ni * 16 + lm;
                int slot = row * 8 + ((c + row) & 7);
                bf0[ni] = *(const bf16x8*)(Bs0 + slot * 8);
            }
#pragma unroll
            for (int mi = 0; mi < 4; ++mi)
#pragma unroll
                for (int ni = 0; ni < 4; ++ni)
                    acc[mi][ni] = __builtin_amdgcn_mfma_f32_16x16x32_bf16(
                        af[mi], bf0[ni], acc[mi][ni], 0, 0, 0);
        }
        __syncthreads();
    }

    // ---- fused scores epilogue ----
    const bool in32 = (flag[0] == 0);
    float tb[4], wc4[4], vv[4];
#pragma unroll
    for (int ni = 0; ni < 4; ++ni) {
        int col = n0 + wn + ni * 16 + lm;
        tb[ni]  = tbias[col];
        wc4[ni] = ldin(Wc, col, in32);
        vv[ni]  = ldin(v, col, in32);
    }
#pragma unroll
    for (int mi = 0; mi < 4; ++mi)
#pragma unroll
        for (int r = 0; r < 4; ++r) {
            int grow = m0 + wm + mi * 16 + q * 4 + r;
            int b    = grow / PN;
            float cv = ldin(cov, grow, in32);
            const float* sp0 = sprojP + (size_t)b * PA;
            float rowsum = 0.f;
#pragma unroll
            for (int ni = 0; ni < 4; ++ni) {
                int col = n0 + wn + ni * 16 + lm;
                float sp = sp0[col] + sp0[PB * PA + col]
                         + sp0[2 * PB * PA + col] + sp0[3 * PB * PA + col];
                float val = acc[mi][ni][r] + sp + tb[ni] + cv * wc4[ni];
                rowsum += vv[ni] * tanhf(val);
            }
#pragma unroll
            for (int off = 1; off < 16; off <<= 1)
                rowsum += __shfl_xor(rowsum, off);
            if (lm == 0) atomicAdd(&sc[grow], rowsum);
        }
}

// elementwise reduce of PLANES bf16 planes -> single bf16, 8 elems/thread
template <int PLANES>
__global__ __launch_bounds__(256) void reduce_kernel(
    const bf16* __restrict__ in, bf16* __restrict__ out, size_t n)
{
    size_t i = ((size_t)blockIdx.x * 256 + threadIdx.x) * 8;
    float s[8] = {0,0,0,0,0,0,0,0};
#pragma unroll
    for (int p = 0; p < PLANES; ++p) {
        bf16x8 v = *(const bf16x8*)(in + (size_t)p * n + i);
#pragma unroll
        for (int j = 0; j < 8; ++j) s[j] += (float)v[j];
    }
    bf16x8 o;
#pragma unroll
    for (int j = 0; j < 8; ++j) o[j] = (bf16)s[j];
    *(bf16x8*)(out + i) = o;
}

// ---------------------------------------------------------------------------
// rowdot: y[c] = sum_k x[k] * Wt[c,k] (+ addv[c]).  One WAVE per output
// element, bf16x8 vector loads, shfl tree reduce.  grid (C/4), block 256.
// ---------------------------------------------------------------------------
__global__ __launch_bounds__(256) void rowdot_kernel(
    const void* __restrict__ x, const bf16* __restrict__ Wt,
    const void* __restrict__ addv, const int* __restrict__ flag, int xMode,
    float* __restrict__ y, int K)
{
    const bool raw32 = (flag[0] == 0);
    const bool x32   = (xMode == 0) || raw32;
    const int wave = threadIdx.x >> 6, lane = threadIdx.x & 63;
    const int c = blockIdx.x * 4 + wave;
    float s = 0.f;
    for (int k0 = lane * 8; k0 < K; k0 += 512) {
        bf16x8 w = *(const bf16x8*)(Wt + (size_t)c * K + k0);
        float xv[8];
        ldx8(x, (size_t)k0, x32, xv);
#pragma unroll
        for (int j = 0; j < 8; ++j) s += xv[j] * (float)w[j];
    }
#pragma unroll
    for (int off = 32; off; off >>= 1) s += __shfl_down(s, off);
    if (lane == 0) {
        float a = addv ? ldin(addv, c, raw32) : 0.f;
        y[c] = s + a;
    }
}

// out[b,h] = cbias[h] + sum_n softmax(sc[b,:])_n * gstar[b*PN+n, h]
// grid (PB), block 256, 4 h/thread.  Output dtype per flag.
__global__ __launch_bounds__(256) void context_kernel(
    const float* __restrict__ sc, const bf16* __restrict__ gstar,
    const float* __restrict__ cbias, const int* __restrict__ flag,
    void* __restrict__ out)
{
    const int b = blockIdx.x, tid = threadIdx.x;
    const int h = tid * 4;
    float e[PN];
    float mx = -1e30f;
    for (int n = 0; n < PN; ++n) mx = fmaxf(mx, sc[b * PN + n]);
    float sum = 0.f;
    for (int n = 0; n < PN; ++n) { e[n] = expf(sc[b * PN + n] - mx); sum += e[n]; }
    const float inv = 1.f / sum;
    f32x4 cb = *(const f32x4*)(cbias + h);
    float acc[4] = {cb[0], cb[1], cb[2], cb[3]};
    for (int n = 0; n < PN; ++n) {
        float al = e[n] * inv;
        bf16v4 g = *(const bf16v4*)(gstar + (size_t)(b * PN + n) * PH + h);
#pragma unroll
        for (int j = 0; j < 4; ++j) acc[j] += al * (float)g[j];
    }
    if (flag[0]) {
        bf16v4 o;
#pragma unroll
        for (int j = 0; j < 4; ++j) o[j] = (bf16)acc[j];
        *(bf16v4*)((bf16*)out + (size_t)b * PH + h) = o;
    } else {
        f32x4 o;
#pragma unroll
        for (int j = 0; j < 4; ++j) o[j] = acc[j];
        *(f32x4*)((float*)out + (size_t)b * PH + h) = o;
    }
}

// ---------------------------------------------------------------------------
extern "C" void kernel_launch(void* const* d_in, const int* in_sizes, int n_in,
                              void* d_out, int out_size, void* d_ws, size_t ws_size,
                              hipStream_t stream)
{
    const void* GF  = d_in[0];
    const void* s_t = d_in[1];
    const void* cov = d_in[2];
    const void* Wg  = d_in[3];
    const void* bg  = d_in[4];
    const void* Wgs = d_in[5];
    const void* bgs = d_in[6];
    const void* Wh  = d_in[7];
    const void* Ws  = d_in[8];
    const void* Wc  = d_in[9];
    const void* v   = d_in[10];
    (void)in_sizes; (void)n_in; (void)out_size; (void)ws_size;

    // ---- workspace plan (peak 132 MiB; lifetime-overlap, same as R4) ----
    const size_t MB = 1u << 20;
    char* W = (char*)d_ws;
    bf16*  GFb    = (bf16*) (W + 0);               // 49 MiB   [S1-S5, fp32 path]
    bf16*  g_star = (bf16*) (W + 0);               // 12.25MiB [S5b-S8], over dead GFb
    int*   flag   = (int*)  (W + 52 * MB);
    float* tbias  = (float*)(W + 52 * MB + 4096);
    float* cbias  = (float*)(W + 52 * MB + 8192);
    float* sc     = (float*)(W + 52 * MB + 12288); // 25 KB
    bf16*  s_tb   = (bf16*) (W + 52 * MB + 262144);// 0.25 MiB [fp32 path]
    bf16*  WsT    = (bf16*) (W + 53 * MB);         // 2 MiB    [S1-S6]
    bf16*  WhT    = (bf16*) (W + 55 * MB);         // 2 MiB    [S1-S7]
    float* sprojP = (float*)(W + 57 * MB);         // 2 MiB (4 planes) [S6-S7]
    bf16*  WgsT   = (bf16*) (W + 59 * MB);         // 8 MiB    [S1-S3]
    bf16*  WggsT  = (bf16*) (W + 59 * MB);         // 8 MiB    [S3b-S5], over dead WgsT
    bf16*  WggsP  = (bf16*) (W + 67 * MB);         // 32 MiB (4 planes) [S3-S3b]
    bf16*  gP     = (bf16*) (W + 67 * MB);         // 49 MiB (4 planes) [S5-S5b]
    bf16*  Wgb    = (bf16*) (W + 100 * MB);        // 32 MiB   [S1-S3, fp32 path] peak = 132 MiB

    dim3 blk(256);

    // 1. merged prep: self-detect + cvt(GF,Wg,s_t) + transpose(Wgs,Wh,Ws)
    //    + sc zeroing.  3 dispatches -> 1; transpose hides under cvt.
    prep_kernel<<<dim3(NCVT + NTRP), blk, 0, stream>>>(
        GF, Wg, s_t, Wgs, Wh, Ws,
        GFb, Wgb, s_tb, WgsT, WhT, WsT,
        flag, sc, PB * PN);

    // 2. cbias = bg@Wgs + bgs;  tbias = cbias@Wh
    rowdot_kernel<<<dim3(PH / 4), blk, 0, stream>>>(bg, WgsT, bgs, flag, 1, cbias, PG);
    rowdot_kernel<<<dim3(PA / 4), blk, 0, stream>>>(cbias, WhT, nullptr, flag, 0, tbias, PH);

    // 3. WggsT[H,G] = WgsT @ Wg^T  (split-K 4 -> 1024 blocks) + reduce4
    gemm_kernel<1><<<dim3(PG / 128, PH / 128, 4), blk, 0, stream>>>(
        WgsT, Wgb, nullptr, Wg, flag, nullptr, WggsP, PH, PG, PG, (PG / 64) / 4);
    reduce_kernel<4><<<dim3((PH * PG) / 2048), blk, 0, stream>>>(
        WggsP, WggsT, (size_t)PH * PG);

    // 5. g_star planes = GF @ Wggs  (split-K 4 -> 1568 blocks) + reduce4
    gemm_kernel<1><<<dim3(PH / 128, PM1 / 128, 4), blk, 0, stream>>>(
        GFb, WggsT, GF, nullptr, flag, nullptr, gP, PM1, PH, PG, (PG / 64) / 4);
    reduce_kernel<4><<<dim3((PM1 * PH) / 2048), blk, 0, stream>>>(
        gP, g_star, (size_t)PM1 * PH);

    // 6. sproj = s_t @ Ws   (split-K 4, fp32 planes; summed in epilogue)
    gemm_kernel<0><<<dim3(PA / 128, 1, 4), blk, 0, stream>>>(
        s_tb, WsT, s_t, nullptr, flag, sprojP, nullptr, PB, PA, PH, (PH / 64) / 4);

    // 7. fused t2-GEMM + scores -> sc  (no split-K; tanh needs full K sum)
    gemm_scores_kernel<<<dim3(PA / 128, PM1 / 128), blk, 0, stream>>>(
        g_star, WhT, sprojP, tbias, cov, Wc, v, flag, sc);

    // 8. context: softmax + weighted sum of g_star + cbias -> out
    context_kernel<<<dim3(PB), blk, 0, stream>>>(sc, g_star, cbias, flag, d_out);
}